// Round 1
// baseline (44294.647 us; speedup 1.0000x reference)
//
#include <hip/hip_runtime.h>
#include <cmath>

#define Bsz 128
#define Ssz 512
#define Isz 512
#define Hsz 1024
#define G4  4096

#define TB 32   // batch tile
#define TH 16   // h-column tile (each carries 4 gate columns)
#define KC 32   // K chunk

__global__ __launch_bounds__(256) void init_state(float* __restrict__ h0,
                                                  float* __restrict__ c,
                                                  float* __restrict__ hsum) {
    int idx = blockIdx.x * 256 + threadIdx.x;
    if (idx < Bsz * Hsz) {
        h0[idx] = 0.f; c[idx] = 0.f; hsum[idx] = 0.f;
    }
}

// One LSTM timestep: gates = [x_t | h_in] @ [W;U] + bias, then elementwise
// state update. Each block owns a 32-batch x 16-hcol tile (all 4 gates), so it
// can finish the c/h update for its columns without further sync.
__global__ __launch_bounds__(256) void lstm_step(
    const float* __restrict__ x, const float* __restrict__ W,
    const float* __restrict__ U, const float* __restrict__ bias,
    int t,
    const float* __restrict__ h_in, float* __restrict__ h_out,
    float* __restrict__ c, float* __restrict__ hsum)
{
    // As: [batch][k], stride 36 keeps float4 alignment + bank spread
    __shared__ float As[TB][36];
    // Bs: [k][col*4 + gate] -> compute reads one float4 per (k, col)
    __shared__ float Bs[KC][68];

    const int tid = threadIdx.x;
    const int tx  = tid & 15;   // h-col within tile
    const int ty  = tid >> 4;   // batch pair 0..15
    const int jH0 = blockIdx.x * TH;
    const int b0  = blockIdx.y * TB;

    const int a_row = tid >> 3;        // 0..31
    const int a_col = (tid & 7) << 2;  // 0,4,...,28

    float acc[2][4] = {{0.f,0.f,0.f,0.f},{0.f,0.f,0.f,0.f}};

    for (int k0 = 0; k0 < Isz + Hsz; k0 += KC) {
        // --- stage A tile (x_t rows for k<512, h rows after) ---
        const float* aptr = (k0 < Isz)
            ? x + ((size_t)(b0 + a_row) * Ssz + t) * Isz + (k0 + a_col)
            : h_in + (size_t)(b0 + a_row) * Hsz + (k0 - Isz + a_col);
        float4 av = *(const float4*)aptr;
        *(float4*)&As[a_row][a_col] = av;

        // --- stage B tile: 32 k-rows x (16 cols x 4 gates), gate-interleaved ---
        #pragma unroll
        for (int it = 0; it < 2; ++it) {
            int lin  = tid + it * 256;
            int krow = lin >> 4;           // 0..31
            int q    = lin & 15;
            int g    = q & 3;              // gate group
            int c0   = (q >> 2) << 2;      // col quad
            const float* bsrc = (k0 < Isz)
                ? W + (size_t)(k0 + krow) * G4
                : U + (size_t)(k0 - Isz + krow) * G4;
            float4 bv = *(const float4*)(bsrc + g * Hsz + jH0 + c0);
            Bs[krow][(c0+0)*4+g] = bv.x;
            Bs[krow][(c0+1)*4+g] = bv.y;
            Bs[krow][(c0+2)*4+g] = bv.z;
            Bs[krow][(c0+3)*4+g] = bv.w;
        }
        __syncthreads();

        #pragma unroll
        for (int kk = 0; kk < KC; ++kk) {
            float a0 = As[2*ty+0][kk];
            float a1 = As[2*ty+1][kk];
            float4 bv = *(const float4*)&Bs[kk][tx << 2];
            acc[0][0] = fmaf(a0, bv.x, acc[0][0]);
            acc[0][1] = fmaf(a0, bv.y, acc[0][1]);
            acc[0][2] = fmaf(a0, bv.z, acc[0][2]);
            acc[0][3] = fmaf(a0, bv.w, acc[0][3]);
            acc[1][0] = fmaf(a1, bv.x, acc[1][0]);
            acc[1][1] = fmaf(a1, bv.y, acc[1][1]);
            acc[1][2] = fmaf(a1, bv.z, acc[1][2]);
            acc[1][3] = fmaf(a1, bv.w, acc[1][3]);
        }
        __syncthreads();
    }

    // --- epilogue: gate activations + state update ---
    const int jH = jH0 + tx;
    const float bf = bias[jH];
    const float bi = bias[Hsz   + jH];
    const float bg = bias[2*Hsz + jH];
    const float bo = bias[3*Hsz + jH];
    #pragma unroll
    for (int r = 0; r < 2; ++r) {
        const int b = b0 + 2*ty + r;
        const size_t idx = (size_t)b * Hsz + jH;
        float gf = acc[r][0] + bf;   // reference gate order: f, i, g, o
        float gi = acc[r][1] + bi;
        float gg = acc[r][2] + bg;
        float go = acc[r][3] + bo;
        float f = 1.f / (1.f + __expf(-gf));
        float i = 1.f / (1.f + __expf(-gi));
        float g = tanhf(gg);
        float o = 1.f / (1.f + __expf(-go));
        float cn = f * c[idx] + i * g;
        c[idx] = cn;
        float hn = o * tanhf(cn);
        h_out[idx] = hn;
        hsum[idx] += hn;
    }
}

__global__ __launch_bounds__(256) void finalize(const float* __restrict__ hsum,
                                                float* __restrict__ out) {
    int idx = blockIdx.x * 256 + threadIdx.x;
    if (idx < Bsz * Hsz)
        out[idx] = hsum[idx] * (1.f / (float)Ssz);
}

extern "C" void kernel_launch(void* const* d_in, const int* in_sizes, int n_in,
                              void* d_out, int out_size, void* d_ws, size_t ws_size,
                              hipStream_t stream) {
    const float* x    = (const float*)d_in[0];
    const float* W    = (const float*)d_in[1];
    const float* U    = (const float*)d_in[2];
    const float* bias = (const float*)d_in[3];
    float* out = (float*)d_out;

    // workspace: h double-buffer, c, hsum  (4 x 512 KB = 2 MB)
    float* h0   = (float*)d_ws;
    float* h1   = h0 + Bsz * Hsz;
    float* c    = h1 + Bsz * Hsz;
    float* hsum = c  + Bsz * Hsz;

    init_state<<<(Bsz*Hsz + 255)/256, 256, 0, stream>>>(h0, c, hsum);

    dim3 grid(Hsz / TH, Bsz / TB);   // 64 x 4 = 256 blocks
    float* hb[2] = {h0, h1};
    for (int t = 0; t < Ssz; ++t) {
        lstm_step<<<grid, 256, 0, stream>>>(x, W, U, bias, t,
                                            hb[t & 1], hb[(t + 1) & 1], c, hsum);
    }

    finalize<<<(Bsz*Hsz + 255)/256, 256, 0, stream>>>(hsum, out);
}

// Round 2
// 8232.669 us; speedup vs baseline: 5.3804x; 5.3804x over previous
//
#include <hip/hip_runtime.h>
#include <cmath>

#define Bsz 128
#define Ssz 512
#define Isz 512
#define Hsz 1024
#define G4  4096
#define Ktot 1536   // I + H

typedef short s8v __attribute__((ext_vector_type(8)));        // 8 bf16 (4 VGPRs)
typedef unsigned short u16x8 __attribute__((ext_vector_type(8)));
typedef float f32x16 __attribute__((ext_vector_type(16)));

__device__ __forceinline__ unsigned short f2bf(float f) {
    unsigned u = __float_as_uint(f);
    u += 0x7fffu + ((u >> 16) & 1u);
    return (unsigned short)(u >> 16);
}
__device__ __forceinline__ float bf2f(unsigned short h) {
    return __uint_as_float(((unsigned)h) << 16);
}
__device__ __forceinline__ float fsig(float v) { return 1.f / (1.f + __expf(-v)); }
__device__ __forceinline__ float ftanh(float v) { return 2.f / (1.f + __expf(-2.f * v)) - 1.f; }

// ---- once per call: W,U -> transposed bf16 hi/lo planes WUt[n][k], k<512 = W, k>=512 = U
__global__ __launch_bounds__(256) void conv_wu(const float* __restrict__ W,
                                               const float* __restrict__ U,
                                               unsigned short* __restrict__ WUthi,
                                               unsigned short* __restrict__ WUtlo) {
    __shared__ float tile[32][33];
    const int tx = threadIdx.x & 31, ty = threadIdx.x >> 5;
    const int nb = blockIdx.x * 32, kb = blockIdx.y * 32;
    #pragma unroll
    for (int r = 0; r < 4; ++r) {
        int k = kb + ty + r * 8;
        float v = (k < Isz) ? W[(size_t)k * G4 + nb + tx]
                            : U[(size_t)(k - Isz) * G4 + nb + tx];
        tile[ty + r * 8][tx] = v;
    }
    __syncthreads();
    #pragma unroll
    for (int r = 0; r < 4; ++r) {
        int nl = ty + r * 8;
        float v = tile[tx][nl];
        unsigned short h = f2bf(v);
        size_t dst = (size_t)(nb + nl) * Ktot + kb + tx;
        WUthi[dst] = h;
        WUtlo[dst] = f2bf(v - bf2f(h));
    }
}

// ---- once per call: zero state, split x[:,0,:]
__global__ __launch_bounds__(256) void lstm_init(const float* __restrict__ x,
                                                 float* __restrict__ c, float* __restrict__ hsum,
                                                 unsigned short* __restrict__ hhi, unsigned short* __restrict__ hlo,
                                                 unsigned short* __restrict__ xthi, unsigned short* __restrict__ xtlo) {
    int idx = blockIdx.x * 256 + threadIdx.x;   // 131072 threads
    c[idx] = 0.f; hsum[idx] = 0.f; hhi[idx] = 0; hlo[idx] = 0;
    if (idx < Bsz * Isz) {
        int b = idx >> 9, i = idx & 511;
        float xv = x[(size_t)b * Ssz * Isz + i];   // t = 0
        unsigned short h = f2bf(xv);
        xthi[idx] = h;
        xtlo[idx] = f2bf(xv - bf2f(h));
    }
}

// ---- per step: partial gates P[kt][m][n] = A[:,kslice] * WUt[kslice,n]
// grid (64 n-tiles, 4 k-slices), 256 threads = 4 waves; wave = M32 x N64 (2x 32x32x16 chains)
#define PITCH 72          // 64 k + 8 pad (u16 elems); 144 B, 16B-aligned
#define A_HI 0
#define A_LO (128 * PITCH)
#define B_HI (2 * 128 * PITCH)
#define B_LO (2 * 128 * PITCH + 64 * PITCH)
#define SMEM_ELEMS (2 * 128 * PITCH + 2 * 64 * PITCH)   // 27648 u16 = 55296 B

__global__ __launch_bounds__(256) void lstm_gates(
    const unsigned short* __restrict__ WUthi, const unsigned short* __restrict__ WUtlo,
    const unsigned short* __restrict__ xthi,  const unsigned short* __restrict__ xtlo,
    const unsigned short* __restrict__ hhi,   const unsigned short* __restrict__ hlo,
    float* __restrict__ P) {
    extern __shared__ unsigned short sm[];
    unsigned short* sAhi = sm + A_HI;
    unsigned short* sAlo = sm + A_LO;
    unsigned short* sBhi = sm + B_HI;
    unsigned short* sBlo = sm + B_LO;

    const int tid = threadIdx.x, lane = tid & 63, w = tid >> 6;
    const int n0 = blockIdx.x * 64, kt = blockIdx.y;

    f32x16 acc0, acc1;
    #pragma unroll
    for (int i = 0; i < 16; ++i) { acc0[i] = 0.f; acc1[i] = 0.f; }

    const int m31  = lane & 31;
    const int koct = (lane >> 5) << 3;                 // 0 or 8
    const int rowA  = (w * 32 + m31) * PITCH + koct;
    const int rowB0 = m31 * PITCH + koct;
    const int rowB1 = rowB0 + 32 * PITCH;

    for (int kc = 0; kc < 6; ++kc) {                   // 6 chunks of K=64
        const int kbase = kt * 384 + kc * 64;
        const bool isX = (kbase < Isz);                // chunk never straddles k=512
        // A: 128 rows x 8 octets -> 4 octets/thread (hi & lo)
        #pragma unroll
        for (int i = 0; i < 4; ++i) {
            int q = i * 256 + tid;
            int row = q >> 3, oct = q & 7;
            int kg = kbase + oct * 8;
            const unsigned short* shi;
            const unsigned short* slo;
            if (isX) { shi = xthi + row * Isz + kg;          slo = xtlo + row * Isz + kg; }
            else     { shi = hhi + row * Hsz + (kg - Isz);   slo = hlo + row * Hsz + (kg - Isz); }
            *(u16x8*)&sAhi[row * PITCH + oct * 8] = *(const u16x8*)shi;
            *(u16x8*)&sAlo[row * PITCH + oct * 8] = *(const u16x8*)slo;
        }
        // B: 64 rows x 8 octets -> 2 octets/thread (hi & lo)
        #pragma unroll
        for (int i = 0; i < 2; ++i) {
            int q = i * 256 + tid;
            int row = q >> 3, oct = q & 7;
            size_t src = (size_t)(n0 + row) * Ktot + kbase + oct * 8;
            *(u16x8*)&sBhi[row * PITCH + oct * 8] = *(const u16x8*)&WUthi[src];
            *(u16x8*)&sBlo[row * PITCH + oct * 8] = *(const u16x8*)&WUtlo[src];
        }
        __syncthreads();
        #pragma unroll
        for (int s = 0; s < 4; ++s) {                  // 4x K16 per chunk
            const int o = s * 16;
            s8v ah  = *(const s8v*)&sAhi[rowA + o];
            s8v al  = *(const s8v*)&sAlo[rowA + o];
            s8v b0h = *(const s8v*)&sBhi[rowB0 + o];
            s8v b0l = *(const s8v*)&sBlo[rowB0 + o];
            s8v b1h = *(const s8v*)&sBhi[rowB1 + o];
            s8v b1l = *(const s8v*)&sBlo[rowB1 + o];
            acc0 = __builtin_amdgcn_mfma_f32_32x32x16_bf16(ah, b0h, acc0, 0, 0, 0);
            acc1 = __builtin_amdgcn_mfma_f32_32x32x16_bf16(ah, b1h, acc1, 0, 0, 0);
            acc0 = __builtin_amdgcn_mfma_f32_32x32x16_bf16(al, b0h, acc0, 0, 0, 0);
            acc1 = __builtin_amdgcn_mfma_f32_32x32x16_bf16(al, b1h, acc1, 0, 0, 0);
            acc0 = __builtin_amdgcn_mfma_f32_32x32x16_bf16(ah, b0l, acc0, 0, 0, 0);
            acc1 = __builtin_amdgcn_mfma_f32_32x32x16_bf16(ah, b1l, acc1, 0, 0, 0);
        }
        __syncthreads();
    }

    // C/D layout (verified m74/m101): col = lane&31, row = (reg&3) + 8*(reg>>2) + 4*(lane>>5)
    float* Pk = P + (size_t)kt * Bsz * G4;
    const int mbase = w * 32 + 4 * (lane >> 5);
    #pragma unroll
    for (int r = 0; r < 16; ++r) {
        int m = mbase + (r & 3) + 8 * (r >> 2);
        Pk[(size_t)m * G4 + n0 + m31]      = acc0[r];
        Pk[(size_t)m * G4 + n0 + 32 + m31] = acc1[r];
    }
}

// ---- per step: combine 4 K-partials, activations, state update, split h (+ next x slice)
__global__ __launch_bounds__(256) void lstm_pointwise(
    const float* __restrict__ P, const float* __restrict__ bias,
    const float* __restrict__ x, int tn,
    float* __restrict__ c, float* __restrict__ hsum,
    unsigned short* __restrict__ hhi, unsigned short* __restrict__ hlo,
    unsigned short* __restrict__ xthi, unsigned short* __restrict__ xtlo) {
    int idx = blockIdx.x * 256 + threadIdx.x;    // 131072 threads
    int b = idx >> 10, j = idx & 1023;
    float gf = 0.f, gi = 0.f, gg = 0.f, go = 0.f;
    #pragma unroll
    for (int s = 0; s < 4; ++s) {
        const float* Pb = P + (((size_t)(s * Bsz + b)) << 12) + j;
        gf += Pb[0];
        gi += Pb[1024];
        gg += Pb[2048];
        go += Pb[3072];
    }
    gf += bias[j]; gi += bias[1024 + j]; gg += bias[2048 + j]; go += bias[3072 + j];
    float f  = fsig(gf);
    float i_ = fsig(gi);
    float g  = ftanh(gg);
    float o  = fsig(go);
    float cn = f * c[idx] + i_ * g;
    c[idx] = cn;
    float hn = o * ftanh(cn);
    hsum[idx] += hn;
    unsigned short hh = f2bf(hn);
    hhi[idx] = hh;
    hlo[idx] = f2bf(hn - bf2f(hh));
    if (tn < Ssz && idx < Bsz * Isz) {
        int bb = idx >> 9, ii = idx & 511;
        float xv = x[((size_t)bb * Ssz + tn) * Isz + ii];
        unsigned short xh = f2bf(xv);
        xthi[idx] = xh;
        xtlo[idx] = f2bf(xv - bf2f(xh));
    }
}

__global__ __launch_bounds__(256) void finalize(const float* __restrict__ hsum,
                                                float* __restrict__ out) {
    int idx = blockIdx.x * 256 + threadIdx.x;
    if (idx < Bsz * Hsz)
        out[idx] = hsum[idx] * (1.f / (float)Ssz);
}

extern "C" void kernel_launch(void* const* d_in, const int* in_sizes, int n_in,
                              void* d_out, int out_size, void* d_ws, size_t ws_size,
                              hipStream_t stream) {
    const float* x    = (const float*)d_in[0];
    const float* W    = (const float*)d_in[1];
    const float* U    = (const float*)d_in[2];
    const float* bias = (const float*)d_in[3];
    float* out = (float*)d_out;

    unsigned char* base = (unsigned char*)d_ws;
    // ws carve (~33.8 MB total)
    unsigned short* WUthi = (unsigned short*)(base);                       // 12,582,912 B
    unsigned short* WUtlo = (unsigned short*)(base + 12582912);            // 12,582,912 B
    float*          P     = (float*)(base + 25165824);                     //  8,388,608 B
    float*          c     = (float*)(base + 33554432);                     //    524,288 B
    float*          hsum  = (float*)(base + 34078720);                     //    524,288 B
    unsigned short* hhi   = (unsigned short*)(base + 34603008);            //    262,144 B
    unsigned short* hlo   = (unsigned short*)(base + 34865152);            //    262,144 B
    unsigned short* xthi  = (unsigned short*)(base + 35127296);            //    131,072 B
    unsigned short* xtlo  = (unsigned short*)(base + 35258368);            //    131,072 B

    conv_wu<<<dim3(G4 / 32, Ktot / 32), 256, 0, stream>>>(W, U, WUthi, WUtlo);
    lstm_init<<<(Bsz * Hsz) / 256, 256, 0, stream>>>(x, c, hsum, hhi, hlo, xthi, xtlo);

    for (int t = 0; t < Ssz; ++t) {
        lstm_gates<<<dim3(64, 4), 256, SMEM_ELEMS * 2, stream>>>(
            WUthi, WUtlo, xthi, xtlo, hhi, hlo, P);
        lstm_pointwise<<<(Bsz * Hsz) / 256, 256, 0, stream>>>(
            P, bias, x, t + 1, c, hsum, hhi, hlo, xthi, xtlo);
    }

    finalize<<<(Bsz * Hsz) / 256, 256, 0, stream>>>(hsum, out);
}